// Round 1
// baseline (660.051 us; speedup 1.0000x reference)
//
#include <hip/hip_runtime.h>
#include <hip/hip_bf16.h>

#define NT 8
#define MEMC 512
#define HID 256
#define C 128   // IN_C == OUT_C

typedef __attribute__((ext_vector_type(8))) short short8;
typedef __attribute__((ext_vector_type(4))) float f32x4;

__device__ inline short f2bf(float f) {
    __hip_bfloat16 h = __float2bfloat16(f);
    union { __hip_bfloat16 b; short s; } u;
    u.b = h;
    return u.s;
}

// ---------------------------------------------------------------------------
// K1: idx init (-1), hist zero, and generator hidden layers h_wg/h_bg [8][256]
// ---------------------------------------------------------------------------
__global__ __launch_bounds__(256) void k1_init_genh(
    const float* __restrict__ edge_feas,
    const float* __restrict__ wg_w1, const float* __restrict__ wg_b1,
    const float* __restrict__ wg_w2, const float* __restrict__ wg_b2,
    const float* __restrict__ bg_w1, const float* __restrict__ bg_b1,
    const float* __restrict__ bg_w2, const float* __restrict__ bg_b2,
    int* __restrict__ hist, int* __restrict__ idx, int idx_cap,
    float* __restrict__ h_wg, float* __restrict__ h_bg,
    int n_init_blocks)
{
    int b = blockIdx.x, tid = threadIdx.x;
    if (b < n_init_blocks) {
        int pos = b * 1024 + tid * 4;
        if (pos < idx_cap) {
            int4 v = make_int4(-1, -1, -1, -1);
            *(int4*)(idx + pos) = v;
        }
        return;
    }
    if (b == n_init_blocks) {
        if (tid < NT) hist[tid] = 0;
        return;
    }
    int gb = b - n_init_blocks - 1;          // 0..15
    int t = gb & 7;
    int gen = gb >> 3;                        // 0 = weight gen, 1 = bias gen
    const float* w1 = gen ? bg_w1 : wg_w1;
    const float* b1 = gen ? bg_b1 : wg_b1;
    const float* w2 = gen ? bg_w2 : wg_w2;
    const float* b2 = gen ? bg_b2 : wg_b2;
    float* hout = gen ? h_bg : h_wg;

    __shared__ float m[MEMC];
    __shared__ float h1[HID];
    m[tid]       = edge_feas[t * MEMC + tid];
    m[tid + 256] = edge_feas[t * MEMC + tid + 256];
    __syncthreads();

    float a0 = b1[tid], a1 = 0.f;
    #pragma unroll 4
    for (int k = 0; k < MEMC; k += 2) {
        a0 += m[k]     * w1[k * HID + tid];
        a1 += m[k + 1] * w1[(k + 1) * HID + tid];
    }
    h1[tid] = fmaxf(a0 + a1, 0.f);
    __syncthreads();

    a0 = b2[tid]; a1 = 0.f;
    #pragma unroll 4
    for (int k = 0; k < HID; k += 2) {
        a0 += h1[k]     * w2[k * HID + tid];
        a1 += h1[k + 1] * w2[(k + 1) * HID + tid];
    }
    hout[t * HID + tid] = fmaxf(a0 + a1, 0.f);
}

// ---------------------------------------------------------------------------
// K2: type histogram + third MLP layer -> W bf16 [t][k][n] (coalesced) + Bias
// ---------------------------------------------------------------------------
__global__ __launch_bounds__(256) void k2_hist_genw(
    const int* __restrict__ type_vec, int N,
    const float* __restrict__ h_wg, const float* __restrict__ h_bg,
    const float* __restrict__ wg_w3, const float* __restrict__ wg_b3,
    const float* __restrict__ bg_w3, const float* __restrict__ bg_b3,
    int* __restrict__ hist, short* __restrict__ Wkn, float* __restrict__ Bias,
    int n_hist_blocks)
{
    int b = blockIdx.x, tid = threadIdx.x;
    if (b < n_hist_blocks) {
        __shared__ int lh[NT];
        if (tid < NT) lh[tid] = 0;
        __syncthreads();
        int base = b * 1024 + tid;
        #pragma unroll
        for (int i = 0; i < 4; ++i) {
            int n = base + i * 256;
            if (n < N) atomicAdd(&lh[type_vec[n]], 1);
        }
        __syncthreads();
        if (tid < NT) atomicAdd(&hist[tid], lh[tid]);
        return;
    }
    int gb = b - n_hist_blocks;
    if (gb < 128) {
        // W = h_wg @ wg_w3 + wg_b3 ; block: 256 cols x 4 types
        int chunk = gb >> 1;                 // 0..63
        int t0 = (gb & 1) * 4;
        __shared__ float h[4][HID];
        for (int i = tid; i < 4 * HID; i += 256)
            h[i >> 8][i & 255] = h_wg[(t0 + (i >> 8)) * HID + (i & 255)];
        __syncthreads();
        int col = chunk * 256 + tid;         // col = k*128 + n, 0..16383
        float a0 = 0.f, a1 = 0.f, a2 = 0.f, a3 = 0.f;
        #pragma unroll 2
        for (int j = 0; j < HID; ++j) {
            float v = wg_w3[j * (C * C) + col];
            a0 += h[0][j] * v;
            a1 += h[1][j] * v;
            a2 += h[2][j] * v;
            a3 += h[3][j] * v;
        }
        float b3 = wg_b3[col];
        Wkn[(t0 + 0) * (C * C) + col] = f2bf(a0 + b3);
        Wkn[(t0 + 1) * (C * C) + col] = f2bf(a1 + b3);
        Wkn[(t0 + 2) * (C * C) + col] = f2bf(a2 + b3);
        Wkn[(t0 + 3) * (C * C) + col] = f2bf(a3 + b3);
        return;
    }
    // bias block
    if (tid < C) {
        for (int t = 0; t < NT; ++t) {
            float acc = bg_b3[tid];
            for (int j = 0; j < HID; ++j)
                acc += h_bg[t * HID + j] * bg_w3[j * C + tid];
            Bias[t * C + tid] = acc;
        }
    }
}

// ---------------------------------------------------------------------------
// K3: scan histogram -> 64-padded segment starts; zero cursors
// ---------------------------------------------------------------------------
__global__ void k3_scan(const int* __restrict__ hist, int* __restrict__ seg,
                        int* __restrict__ cursor)
{
    if (threadIdx.x == 0) {
        int s = 0;
        for (int t = 0; t < NT; ++t) {
            seg[t] = s;
            s += ((hist[t] + 63) >> 6) << 6;
        }
        seg[NT] = s;
    }
    if (threadIdx.x < NT) cursor[threadIdx.x * 16] = 0;
}

// ---------------------------------------------------------------------------
// K4: ballot-based scatter of node ids into type-sorted idx[] + W transpose
//     Wkn [t][k][n] -> Wt [t][n][k]  (B-fragment wants k-contiguous)
// ---------------------------------------------------------------------------
__global__ __launch_bounds__(256) void k4_scatter_transpose(
    const int* __restrict__ type_vec, int N,
    const int* __restrict__ seg, int* __restrict__ cursor,
    int* __restrict__ idx,
    const short* __restrict__ Wkn, short* __restrict__ Wt,
    int n_scatter_blocks)
{
    int b = blockIdx.x, tid = threadIdx.x;
    if (b >= n_scatter_blocks) {
        int t = b - n_scatter_blocks;        // 0..7
        __shared__ short tile[C][C + 8];
        const short* src = Wkn + t * (C * C);
        for (int i = tid; i < C * C; i += 256)
            tile[i >> 7][i & 127] = src[i];  // tile[k][n]
        __syncthreads();
        short* dst = Wt + t * (C * C);
        for (int i = tid; i < C * C; i += 256)
            dst[i] = tile[i & 127][i >> 7];  // dst[n*128 + k] = W[k][n]
        return;
    }
    int lane = tid & 63;
    int wave = b * 4 + (tid >> 6);
    int start = wave * 1024;
    if (start >= N) return;

    // phase 1: count per type over this wave's 1024 nodes
    int cnt[NT];
    #pragma unroll
    for (int t = 0; t < NT; ++t) cnt[t] = 0;
    for (int c = 0; c < 16; ++c) {
        int n = start + c * 64 + lane;
        int mt = (n < N) ? type_vec[n] : NT;
        #pragma unroll
        for (int t = 0; t < NT; ++t)
            cnt[t] += __popcll(__ballot(mt == t));
    }
    // phase 2: reserve ranges (one atomic instr, 8 lanes -> 8 cursors)
    int base = 0;
    if (lane < NT) base = atomicAdd(&cursor[lane * 16], cnt[lane]);
    int run[NT];
    #pragma unroll
    for (int t = 0; t < NT; ++t) run[t] = seg[t] + __shfl(base, t, 64);
    // phase 3: write positions
    unsigned long long below = (1ULL << lane) - 1ULL;
    for (int c = 0; c < 16; ++c) {
        int n = start + c * 64 + lane;
        int mt = (n < N) ? type_vec[n] : NT;
        int mypos = 0;
        #pragma unroll
        for (int t = 0; t < NT; ++t) {
            unsigned long long msk = __ballot(mt == t);
            if (mt == t) mypos = run[t] + __popcll(msk & below);
            run[t] += __popcll(msk);
        }
        if (n < N) idx[mypos] = n;
    }
}

// ---------------------------------------------------------------------------
// K5: the GEMM. 64-row type-uniform tiles, 4 waves M-split, no LDS.
//     out[idx[p]] = bf16(x[idx[p]]) @ Wt[t] + Bias[t]
// ---------------------------------------------------------------------------
__global__ __launch_bounds__(256) void k5_gemm(
    const float* __restrict__ x, const int* __restrict__ idx,
    const short* __restrict__ Wt, const float* __restrict__ Bias,
    const int* __restrict__ seg, float* __restrict__ out)
{
    int tid = threadIdx.x;
    int lane = tid & 63;
    int w = tid >> 6;                        // wave 0..3 -> rows 16w..16w+15
    int block_base = blockIdx.x * 64;
    int total = seg[NT];
    if (block_base >= total) return;

    int t = 0;
    #pragma unroll
    for (int i = 1; i < NT; ++i)
        if (block_base >= seg[i]) t = i;

    int quad = lane >> 4;
    int m16 = lane & 15;
    const short* Wtt = Wt + t * (C * C);

    int arow = idx[block_base + 16 * w + m16];
    bool avalid = arow >= 0;
    const float* xrow = x + (size_t)(avalid ? arow : 0) * C;

    f32x4 acc[8];
    #pragma unroll
    for (int i = 0; i < 8; ++i) acc[i] = (f32x4){0.f, 0.f, 0.f, 0.f};

    #pragma unroll
    for (int kk = 0; kk < 4; ++kk) {
        int k0 = kk * 32 + quad * 8;
        short8 afrag;
        if (avalid) {
            float4 a0 = *(const float4*)(xrow + k0);
            float4 a1 = *(const float4*)(xrow + k0 + 4);
            afrag[0] = f2bf(a0.x); afrag[1] = f2bf(a0.y);
            afrag[2] = f2bf(a0.z); afrag[3] = f2bf(a0.w);
            afrag[4] = f2bf(a1.x); afrag[5] = f2bf(a1.y);
            afrag[6] = f2bf(a1.z); afrag[7] = f2bf(a1.w);
        } else {
            afrag = (short8){0, 0, 0, 0, 0, 0, 0, 0};
        }
        #pragma unroll
        for (int ni = 0; ni < 8; ++ni) {
            short8 bfrag = *(const short8*)(Wtt + (ni * 16 + m16) * C + k0);
            acc[ni] = __builtin_amdgcn_mfma_f32_16x16x32_bf16(afrag, bfrag, acc[ni], 0, 0, 0);
        }
    }

    float bv[8];
    #pragma unroll
    for (int ni = 0; ni < 8; ++ni) bv[ni] = Bias[t * C + ni * 16 + m16];

    int p0 = block_base + 16 * w + quad * 4;
    #pragma unroll
    for (int r = 0; r < 4; ++r) {
        int node = idx[p0 + r];
        if (node < 0) continue;
        float* orow = out + (size_t)node * C;
        #pragma unroll
        for (int ni = 0; ni < 8; ++ni)
            orow[ni * 16 + m16] = acc[ni][r] + bv[ni];
    }
}

// ---------------------------------------------------------------------------
extern "C" void kernel_launch(void* const* d_in, const int* in_sizes, int n_in,
                              void* d_out, int out_size, void* d_ws, size_t ws_size,
                              hipStream_t stream)
{
    const float* x         = (const float*)d_in[0];
    const int*   type_vec  = (const int*)d_in[1];
    const float* edge_feas = (const float*)d_in[2];
    const float* wg_w1 = (const float*)d_in[3];
    const float* wg_b1 = (const float*)d_in[4];
    const float* wg_w2 = (const float*)d_in[5];
    const float* wg_b2 = (const float*)d_in[6];
    const float* wg_w3 = (const float*)d_in[7];
    const float* wg_b3 = (const float*)d_in[8];
    const float* bg_w1 = (const float*)d_in[9];
    const float* bg_b1 = (const float*)d_in[10];
    const float* bg_w2 = (const float*)d_in[11];
    const float* bg_b2 = (const float*)d_in[12];
    const float* bg_w3 = (const float*)d_in[13];
    const float* bg_b3 = (const float*)d_in[14];
    float* out = (float*)d_out;
    int N = in_sizes[1];

    // workspace layout (bytes)
    char* ws = (char*)d_ws;
    int*   hist   = (int*)(ws + 0);        // 8 ints
    int*   seg    = (int*)(ws + 64);       // 9 ints
    int*   cursor = (int*)(ws + 128);      // 8 ints, 64B stride each
    float* h_wg   = (float*)(ws + 1024);   // 8*256 f32
    float* h_bg   = (float*)(ws + 9216);   // 8*256 f32
    float* Bias   = (float*)(ws + 17408);  // 8*128 f32
    short* Wkn    = (short*)(ws + 21504);  // 8*128*128 bf16 [t][k][n]
    short* Wt     = (short*)(ws + 283648); // 8*128*128 bf16 [t][n][k]
    int*   idx    = (int*)(ws + 545792);   // (ceil(N/64)+8)*64 ints

    int nblk64  = (N + 63) / 64;
    int idx_cap = (nblk64 + 8) * 64;
    int n_init  = (idx_cap + 1023) / 1024;
    int n_hist  = (N + 1023) / 1024;
    int n_scat  = (n_hist + 3) / 4;

    k1_init_genh<<<n_init + 17, 256, 0, stream>>>(
        edge_feas, wg_w1, wg_b1, wg_w2, wg_b2, bg_w1, bg_b1, bg_w2, bg_b2,
        hist, idx, idx_cap, h_wg, h_bg, n_init);

    k2_hist_genw<<<n_hist + 129, 256, 0, stream>>>(
        type_vec, N, h_wg, h_bg, wg_w3, wg_b3, bg_w3, bg_b3,
        hist, Wkn, Bias, n_hist);

    k3_scan<<<1, 64, 0, stream>>>(hist, seg, cursor);

    k4_scatter_transpose<<<n_scat + 8, 256, 0, stream>>>(
        type_vec, N, seg, cursor, idx, Wkn, Wt, n_scat);

    k5_gemm<<<nblk64 + 8, 256, 0, stream>>>(x, idx, Wt, Bias, seg, out);
}

// Round 2
// 544.928 us; speedup vs baseline: 1.2113x; 1.2113x over previous
//
#include <hip/hip_runtime.h>
#include <hip/hip_bf16.h>

#define NT 8
#define MEMC 512
#define HID 256
#define C 128   // IN_C == OUT_C

typedef __attribute__((ext_vector_type(8))) short short8;
typedef __attribute__((ext_vector_type(4))) short short4v;
typedef __attribute__((ext_vector_type(4))) float f32x4;

__device__ inline short f2bf(float f) {
    union { __hip_bfloat16 b; short s; } u;
    u.b = __float2bfloat16(f);
    return u.s;
}

// ---------------------------------------------------------------------------
// K1: idx init (-1), hist+cursor zero, generator hidden layers h_wg/h_bg
//     [8][256].  Generator blocks: 4-way wave K-split + LDS reduce.
// ---------------------------------------------------------------------------
__global__ __launch_bounds__(256) void k1_init_genh(
    const float* __restrict__ edge_feas,
    const float* __restrict__ wg_w1, const float* __restrict__ wg_b1,
    const float* __restrict__ wg_w2, const float* __restrict__ wg_b2,
    const float* __restrict__ bg_w1, const float* __restrict__ bg_b1,
    const float* __restrict__ bg_w2, const float* __restrict__ bg_b2,
    int* __restrict__ hist, int* __restrict__ cursor,
    int* __restrict__ idx, int idx_cap,
    float* __restrict__ h_wg, float* __restrict__ h_bg,
    int n_init_blocks)
{
    int b = blockIdx.x, tid = threadIdx.x;
    if (b < n_init_blocks) {
        int pos = b * 1024 + tid * 4;
        if (pos < idx_cap) *(int4*)(idx + pos) = make_int4(-1, -1, -1, -1);
        return;
    }
    if (b == n_init_blocks) {
        if (tid < NT) { hist[tid] = 0; cursor[tid * 16] = 0; }
        return;
    }
    int gb = b - n_init_blocks - 1;          // 0..15
    int t = gb & 7;
    int gen = gb >> 3;
    const float* w1 = gen ? bg_w1 : wg_w1;
    const float* b1 = gen ? bg_b1 : wg_b1;
    const float* w2 = gen ? bg_w2 : wg_w2;
    const float* b2 = gen ? bg_b2 : wg_b2;
    float* hout = gen ? h_bg : h_wg;

    __shared__ float m[MEMC];
    __shared__ float part[4][HID];
    __shared__ float h1[HID];
    m[tid]       = edge_feas[t * MEMC + tid];
    m[tid + 256] = edge_feas[t * MEMC + tid + 256];
    __syncthreads();

    int w = tid >> 6, l = tid & 63;
    // layer 1: K=512, wave w owns k in [w*128, w*128+128)
    {
        float ax = 0.f, ay = 0.f, az = 0.f, aw = 0.f;
        const float* wp = w1 + (size_t)(w * 128) * HID + 4 * l;
        #pragma unroll 8
        for (int k = 0; k < 128; ++k) {
            float4 v = *(const float4*)(wp + (size_t)k * HID);
            float mk = m[w * 128 + k];
            ax += mk * v.x; ay += mk * v.y; az += mk * v.z; aw += mk * v.w;
        }
        *(float4*)&part[w][4 * l] = make_float4(ax, ay, az, aw);
    }
    __syncthreads();
    {
        float s = part[0][tid] + part[1][tid] + part[2][tid] + part[3][tid] + b1[tid];
        h1[tid] = fmaxf(s, 0.f);
    }
    __syncthreads();
    // layer 2: K=256, wave w owns k in [w*64, w*64+64)
    {
        float ax = 0.f, ay = 0.f, az = 0.f, aw = 0.f;
        const float* wp = w2 + (size_t)(w * 64) * HID + 4 * l;
        #pragma unroll 8
        for (int k = 0; k < 64; ++k) {
            float4 v = *(const float4*)(wp + (size_t)k * HID);
            float hk = h1[w * 64 + k];
            ax += hk * v.x; ay += hk * v.y; az += hk * v.z; aw += hk * v.w;
        }
        *(float4*)&part[w][4 * l] = make_float4(ax, ay, az, aw);
    }
    __syncthreads();
    {
        float s = part[0][tid] + part[1][tid] + part[2][tid] + part[3][tid] + b2[tid];
        hout[t * HID + tid] = fmaxf(s, 0.f);
    }
}

// ---------------------------------------------------------------------------
// K2: type histogram + third layers.
//   W blocks (256): 64 cols each, 4-way K-split, 8 types per load.
//   Bias block (1): 128 cols, 2-way K-split, 8 types per load.
// ---------------------------------------------------------------------------
__global__ __launch_bounds__(256) void k2_hist_genw(
    const int* __restrict__ type_vec, int N,
    const float* __restrict__ h_wg, const float* __restrict__ h_bg,
    const float* __restrict__ wg_w3, const float* __restrict__ wg_b3,
    const float* __restrict__ bg_w3, const float* __restrict__ bg_b3,
    int* __restrict__ hist, short* __restrict__ Wkn, float* __restrict__ Bias,
    int n_hist_blocks)
{
    int b = blockIdx.x, tid = threadIdx.x;
    __shared__ float sh[2048];
    __shared__ float sp[2048];
    if (b < n_hist_blocks) {
        __shared__ int lh[NT];
        if (tid < NT) lh[tid] = 0;
        __syncthreads();
        int base = b * 1024 + tid;
        #pragma unroll
        for (int i = 0; i < 4; ++i) {
            int n = base + i * 256;
            if (n < N) atomicAdd(&lh[type_vec[n]], 1);
        }
        __syncthreads();
        if (tid < NT) atomicAdd(&hist[tid], lh[tid]);
        return;
    }
    int gb = b - n_hist_blocks;
    if (gb < 256) {
        for (int i = tid; i < 2048; i += 256) sh[i] = h_wg[i];
        __syncthreads();
        int cl = tid & 63, p = tid >> 6;
        int col = gb * 64 + cl;
        float acc[NT];
        #pragma unroll
        for (int t = 0; t < NT; ++t) acc[t] = 0.f;
        const float* wp = wg_w3 + (size_t)(p * 64) * (C * C) + col;
        #pragma unroll 8
        for (int j = 0; j < 64; ++j) {
            float v = wp[(size_t)j * (C * C)];
            #pragma unroll
            for (int t = 0; t < NT; ++t) acc[t] += sh[t * 256 + p * 64 + j] * v;
        }
        #pragma unroll
        for (int t = 0; t < NT; ++t) sp[p * 512 + t * 64 + cl] = acc[t];
        __syncthreads();
        #pragma unroll
        for (int r = 0; r < 2; ++r) {
            int o = tid + 256 * r;               // 0..511
            int t = o >> 6, c2 = o & 63;
            float s = sp[t * 64 + c2] + sp[512 + t * 64 + c2]
                    + sp[1024 + t * 64 + c2] + sp[1536 + t * 64 + c2]
                    + wg_b3[gb * 64 + c2];
            Wkn[t * (C * C) + gb * 64 + c2] = f2bf(s);
        }
        return;
    }
    // bias block
    for (int i = tid; i < 2048; i += 256) sh[i] = h_bg[i];
    __syncthreads();
    int cl = tid & 127, p = tid >> 7;
    float acc[NT];
    #pragma unroll
    for (int t = 0; t < NT; ++t) acc[t] = 0.f;
    const float* wp = bg_w3 + (size_t)(p * 128) * C + cl;
    #pragma unroll 8
    for (int j = 0; j < 128; ++j) {
        float v = wp[(size_t)j * C];
        #pragma unroll
        for (int t = 0; t < NT; ++t) acc[t] += sh[t * 256 + p * 128 + j] * v;
    }
    #pragma unroll
    for (int t = 0; t < NT; ++t) sp[p * 1024 + t * 128 + cl] = acc[t];
    __syncthreads();
    #pragma unroll
    for (int r = 0; r < 4; ++r) {
        int o = tid + 256 * r;                   // 0..1023
        int t = o >> 7, c2 = o & 127;
        Bias[t * C + c2] = sp[t * 128 + c2] + sp[1024 + t * 128 + c2] + bg_b3[c2];
    }
}

// ---------------------------------------------------------------------------
// K4: ballot scatter into type-sorted idx[] (seg computed inline from hist)
//     + W transpose Wkn[t][k][n] -> Wt[t][n][k]
// ---------------------------------------------------------------------------
__global__ __launch_bounds__(256) void k4_scatter_transpose(
    const int* __restrict__ type_vec, int N,
    const int* __restrict__ hist, int* __restrict__ cursor,
    int* __restrict__ idx,
    const short* __restrict__ Wkn, short* __restrict__ Wt,
    int n_scatter_blocks)
{
    int b = blockIdx.x, tid = threadIdx.x;
    if (b >= n_scatter_blocks) {
        int t = b - n_scatter_blocks;            // 0..7
        __shared__ short tile[C][C + 8];
        const short* src = Wkn + t * (C * C);
        for (int i = tid; i < C * C; i += 256)
            tile[i >> 7][i & 127] = src[i];
        __syncthreads();
        short* dst = Wt + t * (C * C);
        for (int i = tid; i < C * C; i += 256)
            dst[i] = tile[i & 127][i >> 7];
        return;
    }
    int seg[NT];
    {
        int s = 0;
        #pragma unroll
        for (int t = 0; t < NT; ++t) { seg[t] = s; s += ((hist[t] + 63) >> 6) << 6; }
    }
    int lane = tid & 63;
    int wave = b * 4 + (tid >> 6);
    int start = wave * 1024;
    if (start >= N) return;

    int cnt[NT];
    #pragma unroll
    for (int t = 0; t < NT; ++t) cnt[t] = 0;
    for (int c = 0; c < 16; ++c) {
        int n = start + c * 64 + lane;
        int mt = (n < N) ? type_vec[n] : NT;
        #pragma unroll
        for (int t = 0; t < NT; ++t)
            cnt[t] += __popcll(__ballot(mt == t));
    }
    int base = 0;
    if (lane < NT) base = atomicAdd(&cursor[lane * 16], cnt[lane]);
    int run[NT];
    #pragma unroll
    for (int t = 0; t < NT; ++t) run[t] = seg[t] + __shfl(base, t, 64);
    unsigned long long below = (1ULL << lane) - 1ULL;
    for (int c = 0; c < 16; ++c) {
        int n = start + c * 64 + lane;
        int mt = (n < N) ? type_vec[n] : NT;
        int mypos = 0;
        #pragma unroll
        for (int t = 0; t < NT; ++t) {
            unsigned long long msk = __ballot(mt == t);
            if (mt == t) mypos = run[t] + __popcll(msk & below);
            run[t] += __popcll(msk);
        }
        if (n < N) idx[mypos] = n;
    }
}

// ---------------------------------------------------------------------------
// K5: LDS-staged GEMM. Block = 64 rows x 128 cols, 4 waves.
//     Coalesced A gather (float4 -> bf16 -> LDS), B staged to LDS once,
//     MFMA frags via ds_read_b128, C through LDS -> coalesced float4 stores.
// ---------------------------------------------------------------------------
#define AS_LD 136           // shorts per As row  (128 + 8 pad, 16B multiple)
#define BS_LD 136           // shorts per Bs row
#define CS_LD 132           // floats per Cs row  (128 + 4 pad, 16B multiple)

__global__ __launch_bounds__(256, 3) void k5_gemm(
    const float* __restrict__ x, const int* __restrict__ idx,
    const short* __restrict__ Wt, const float* __restrict__ Bias,
    const int* __restrict__ hist, float* __restrict__ out)
{
    __shared__ __align__(16) char smem[64 * AS_LD * 2 + 128 * BS_LD * 2];
    short (*As)[AS_LD] = (short(*)[AS_LD])smem;
    short (*Bs)[BS_LD] = (short(*)[BS_LD])(smem + 64 * AS_LD * 2);
    float (*Cs)[CS_LD] = (float(*)[CS_LD])(smem + 64 * AS_LD * 2);  // aliases Bs
    __shared__ int ridx[64];

    int tid = threadIdx.x;
    int lane = tid & 63, w = tid >> 6;
    int block_base = blockIdx.x * 64;

    int seg[NT + 1];
    {
        int s = 0;
        #pragma unroll
        for (int t = 0; t < NT; ++t) { seg[t] = s; s += ((hist[t] + 63) >> 6) << 6; }
        seg[NT] = s;
    }
    if (block_base >= seg[NT]) return;
    int t = 0;
    #pragma unroll
    for (int i = 1; i < NT; ++i)
        if (block_base >= seg[i]) t = i;

    if (tid < 64) ridx[tid] = idx[block_base + tid];
    __syncthreads();

    // ---- stage A: wave w covers rows 16w..16w+15, 2 rows per iter ----
    {
        int rbase = 16 * w + (lane >> 5);
        int c4 = (lane & 31) * 4;
        #pragma unroll
        for (int i = 0; i < 8; ++i) {
            int r = rbase + i * 2;
            int node = ridx[r];
            float4 v = make_float4(0.f, 0.f, 0.f, 0.f);
            if (node >= 0) v = *(const float4*)(x + (size_t)node * C + c4);
            short4v sv;
            sv[0] = f2bf(v.x); sv[1] = f2bf(v.y);
            sv[2] = f2bf(v.z); sv[3] = f2bf(v.w);
            *(short4v*)&As[r][c4] = sv;
        }
    }
    // ---- stage B: wave w covers rows w*32..w*32+31, 4 rows per iter ----
    {
        int rr = w * 32 + (lane >> 4);
        int c8 = (lane & 15) * 8;
        const short* src = Wt + t * (C * C);
        #pragma unroll
        for (int i = 0; i < 8; ++i) {
            int r = rr + i * 4;
            short8 v = *(const short8*)(src + r * C + c8);
            *(short8*)&Bs[r][c8] = v;
        }
    }
    __syncthreads();

    int quad = lane >> 4, m16 = lane & 15;
    float bv[8];
    #pragma unroll
    for (int ni = 0; ni < 8; ++ni) bv[ni] = Bias[t * C + ni * 16 + m16];

    f32x4 acc[8];
    #pragma unroll
    for (int i = 0; i < 8; ++i) acc[i] = (f32x4){0.f, 0.f, 0.f, 0.f};

    #pragma unroll
    for (int kk = 0; kk < 4; ++kk) {
        short8 af = *(const short8*)&As[16 * w + m16][kk * 32 + quad * 8];
        #pragma unroll
        for (int ni = 0; ni < 8; ++ni) {
            short8 bf = *(const short8*)&Bs[ni * 16 + m16][kk * 32 + quad * 8];
            acc[ni] = __builtin_amdgcn_mfma_f32_16x16x32_bf16(af, bf, acc[ni], 0, 0, 0);
        }
    }
    __syncthreads();   // all Bs reads done before Cs overwrites the region

    #pragma unroll
    for (int ni = 0; ni < 8; ++ni) {
        int colc = ni * 16 + m16;
        #pragma unroll
        for (int r = 0; r < 4; ++r)
            Cs[16 * w + quad * 4 + r][colc] = acc[ni][r] + bv[ni];
    }
    __syncthreads();

    // ---- coalesced store: 2 rows per iter ----
    {
        int rbase = 16 * w + (lane >> 5);
        int c4 = (lane & 31) * 4;
        #pragma unroll
        for (int i = 0; i < 8; ++i) {
            int r = rbase + i * 2;
            int node = ridx[r];
            if (node >= 0) {
                float4 v = *(const float4*)&Cs[r][c4];
                *(float4*)(out + (size_t)node * C + c4) = v;
            }
        }
    }
}

// ---------------------------------------------------------------------------
extern "C" void kernel_launch(void* const* d_in, const int* in_sizes, int n_in,
                              void* d_out, int out_size, void* d_ws, size_t ws_size,
                              hipStream_t stream)
{
    const float* x         = (const float*)d_in[0];
    const int*   type_vec  = (const int*)d_in[1];
    const float* edge_feas = (const float*)d_in[2];
    const float* wg_w1 = (const float*)d_in[3];
    const float* wg_b1 = (const float*)d_in[4];
    const float* wg_w2 = (const float*)d_in[5];
    const float* wg_b2 = (const float*)d_in[6];
    const float* wg_w3 = (const float*)d_in[7];
    const float* wg_b3 = (const float*)d_in[8];
    const float* bg_w1 = (const float*)d_in[9];
    const float* bg_b1 = (const float*)d_in[10];
    const float* bg_w2 = (const float*)d_in[11];
    const float* bg_b2 = (const float*)d_in[12];
    const float* bg_w3 = (const float*)d_in[13];
    const float* bg_b3 = (const float*)d_in[14];
    float* out = (float*)d_out;
    int N = in_sizes[1];

    char* ws = (char*)d_ws;
    int*   hist   = (int*)(ws + 0);        // 8 ints
    int*   cursor = (int*)(ws + 128);      // 8 ints, 64B stride
    float* h_wg   = (float*)(ws + 1024);   // 8*256 f32
    float* h_bg   = (float*)(ws + 9216);   // 8*256 f32
    float* Bias   = (float*)(ws + 17408);  // 8*128 f32
    short* Wkn    = (short*)(ws + 21504);  // 8*128*128 bf16 [t][k][n]
    short* Wt     = (short*)(ws + 283648); // 8*128*128 bf16 [t][n][k]
    int*   idx    = (int*)(ws + 545792);   // (ceil(N/64)+8)*64 ints

    int nblk64  = (N + 63) / 64;
    int idx_cap = (nblk64 + 8) * 64;
    int n_init  = (idx_cap + 1023) / 1024;
    int n_hist  = (N + 1023) / 1024;
    int n_scat  = (n_hist + 3) / 4;

    k1_init_genh<<<n_init + 17, 256, 0, stream>>>(
        edge_feas, wg_w1, wg_b1, wg_w2, wg_b2, bg_w1, bg_b1, bg_w2, bg_b2,
        hist, cursor, idx, idx_cap, h_wg, h_bg, n_init);

    k2_hist_genw<<<n_hist + 257, 256, 0, stream>>>(
        type_vec, N, h_wg, h_bg, wg_w3, wg_b3, bg_w3, bg_b3,
        hist, Wkn, Bias, n_hist);

    k4_scatter_transpose<<<n_scat + 8, 256, 0, stream>>>(
        type_vec, N, hist, cursor, idx, Wkn, Wt, n_scat);

    k5_gemm<<<nblk64 + 8, 256, 0, stream>>>(x, idx, Wt, Bias, hist, out);
}